// Round 4
// baseline (999.063 us; speedup 1.0000x reference)
//
#include <hip/hip_runtime.h>
#include <stdint.h>

typedef _Float16 f16x8 __attribute__((ext_vector_type(8)));
typedef float    f32x4 __attribute__((ext_vector_type(4)));

#define DEVFN static __device__ __forceinline__

DEVFN unsigned short f2hu(float f) {
  _Float16 h = (_Float16)f;
  return __builtin_bit_cast(unsigned short, h);
}
DEVFN float h2f(unsigned short u) {
  return (float)__builtin_bit_cast(_Float16, u);
}
DEVFN float lrelu(float v) { return v >= 0.f ? v : 0.1f * v; }

DEVFN void gload16(const void* g, const void* l) {
  __builtin_amdgcn_global_load_lds(
      (const __attribute__((address_space(1))) void*)(uintptr_t)g,
      (__attribute__((address_space(3))) void*)(uint32_t)(uintptr_t)l,
      16, 0, 0);
}

static constexpr float SCALE_C = 0.029462782549439476f;  // 1/sqrt(128*9)

// ---------------- workspace layout (bytes) — identical footprint to round 3 ----------------
static constexpr size_t OFF_SIN  = 0;        // 1024 f32: s_in[b,ci]
static constexpr size_t OFF_DS   = 4096;     // 1024 f32: dscale[b,co]
static constexpr size_t OFF_ZERO = 8192;     // 512B zeros (drift-safe halo source)
static constexpr size_t OFF_W2   = 12288;    // 16384 f32: W2[co,ci]
static constexpr size_t OFF_WPK  = 77824;    // 4 x 147456 fp16 packed [co][tap][ci]
static constexpr size_t OFF_WB   = OFF_WPK + 4ull * 147456ull * 2ull;          // w_bottle fp16 [co][256]
static constexpr size_t OFF_XCAT = OFF_WB + 65536;                             // NHWC fp16 [8][128][128][256]
static constexpr size_t OFF_XB   = OFF_XCAT + 8ull * 16384ull * 256ull * 2ull; // [8][128][128][128]
static constexpr size_t OFF_Y1   = OFF_XB + 8ull * 16384ull * 128ull * 2ull;

// ---------------- prep1: weight packs + s_in + W2 + zeros ----------------
__global__ __launch_bounds__(256) void prep1_kernel(
    const float* __restrict__ xg, const float* __restrict__ w_mod,
    const float* __restrict__ b_mod, const float* __restrict__ w_style,
    const float* __restrict__ w_dc1, const float* __restrict__ w_dc2,
    const float* __restrict__ w_last, const float* __restrict__ w_bottle,
    unsigned short* __restrict__ wpk, unsigned short* __restrict__ wb,
    float* __restrict__ s_in, float* __restrict__ w2buf,
    float* __restrict__ zerob) {
  const int idx = (int)blockIdx.x * 256 + (int)threadIdx.x;
  if (idx < 589824) {  // pack 4 3x3 weights [co][ci][3][3] -> [co][tap][ci] fp16
    const int t  = idx / 147456;
    const int e  = idx - t * 147456;
    const int co = e / 1152;
    const int r  = e - co * 1152;
    const int tap = r >> 7;
    const int ci  = r & 127;
    const float* src = (t == 0) ? w_dc1 : (t == 1) ? w_dc2 : (t == 2) ? w_style : w_last;
    wpk[idx] = f2hu(src[(size_t)(co * 128 + ci) * 9 + tap]);
    return;
  }
  int j = idx - 589824;
  if (j < 32768) { wb[j] = f2hu(w_bottle[j]); return; }
  j -= 32768;
  if (j < 65536) {  // one wave per (b,ci): s_in = b_mod + xg·w_mod
    const int pair = j >> 6, ln = j & 63;
    const int b = pair >> 7, ci = pair & 127;
    float st = 0.f;
    for (int m = ln; m < 512; m += 64) st += xg[b * 512 + m] * w_mod[ci * 512 + m];
    for (int off = 32; off > 0; off >>= 1) st += __shfl_down(st, off);
    if (ln == 0) s_in[pair] = st + b_mod[ci];
    return;
  }
  j -= 65536;
  if (j < 16384) {  // W2[co,ci] = sum_tap w_style^2
    float acc = 0.f;
#pragma unroll
    for (int t = 0; t < 9; ++t) { float w = w_style[(size_t)j * 9 + t]; acc += w * w; }
    w2buf[j] = acc;
    return;
  }
  j -= 16384;
  if (j < 128) zerob[j] = 0.f;
}

// ---------------- prep2: dscale[b,co] ----------------
__global__ __launch_bounds__(256) void prep2_kernel(
    const float* __restrict__ s_in, const float* __restrict__ w2buf,
    float* __restrict__ dscale) {
  const int j = (int)blockIdx.x * 256 + (int)threadIdx.x;
  const int pair = j >> 6, ln = j & 63;
  const int b = pair >> 7, co = pair & 127;
  const float s0 = s_in[b * 128 + ln];
  const float s1 = s_in[b * 128 + 64 + ln];
  float acc = s0 * s0 * w2buf[co * 128 + ln] + s1 * s1 * w2buf[co * 128 + 64 + ln];
  for (int off = 32; off > 0; off >>= 1) acc += __shfl_down(acc, off);
  if (ln == 0)
    dscale[pair] = SCALE_C * rsqrtf(SCALE_C * SCALE_C * acc + 1e-8f);
}

// ---------------- upcat v2: 64-px half-rows, 33KB LDS, contiguous packed stores ----------------
__global__ __launch_bounds__(256) void upcat2_kernel(
    const float* __restrict__ x2, const float* __restrict__ x1,
    unsigned short* __restrict__ xcat) {
  __shared__ unsigned short lt[256][65];
  const int bid = (int)blockIdx.x;
  const int b = bid >> 8, h = (bid >> 1) & 127, w0 = (bid & 1) << 6;
  const int tid = (int)threadIdx.x;
  const int cr = tid >> 4, wq = tid & 15;

  // x2 -> channels 0..127
#pragma unroll
  for (int p = 0; p < 8; ++p) {
    const int c = p * 16 + cr;
    const float4 v = *(const float4*)(x2 + ((size_t)(b * 128 + c) * 16384 + h * 128 + w0 + wq * 4));
    lt[c][wq * 4 + 0] = f2hu(v.x);
    lt[c][wq * 4 + 1] = f2hu(v.y);
    lt[c][wq * 4 + 2] = f2hu(v.z);
    lt[c][wq * 4 + 3] = f2hu(v.w);
  }
  // x1 bilinear 2x (half-pixel) -> channels 128..255
  const int m = h >> 1;
  const bool oh = (h & 1);
  const int ly = oh ? m : m - 1;
  const float fy = oh ? 0.25f : 0.75f;
  const int y0 = ly < 0 ? 0 : ly;
  const int y1 = (ly + 1) > 63 ? 63 : (ly + 1);
#pragma unroll
  for (int p = 0; p < 8; ++p) {
    const int c = p * 16 + cr;
    const float* r0 = x1 + ((size_t)(b * 128 + c) * 4096 + y0 * 64);
    const float* r1 = x1 + ((size_t)(b * 128 + c) * 4096 + y1 * 64);
#pragma unroll
    for (int k = 0; k < 4; ++k) {
      const int w = w0 + wq * 4 + k;
      const int n = w >> 1;
      const bool ow = (w & 1);
      const int lx = ow ? n : n - 1;
      const float fx = ow ? 0.25f : 0.75f;
      const int x0i = lx < 0 ? 0 : lx;
      const int x1i = (lx + 1) > 63 ? 63 : (lx + 1);
      const float vy0 = (1.f - fx) * r0[x0i] + fx * r0[x1i];
      const float vy1 = (1.f - fx) * r1[x0i] + fx * r1[x1i];
      lt[128 + c][wq * 4 + k] = f2hu((1.f - fy) * vy0 + fy * vy1);
    }
  }
  __syncthreads();
  // out: uint-packed channel pairs; wave writes contiguous 128B segments
  const int cp = tid & 31, pr = tid >> 5;
  unsigned int* outp = (unsigned int*)(xcat + ((size_t)((b * 128 + h) * 128 + w0)) * 256);
#pragma unroll
  for (int cpass = 0; cpass < 4; ++cpass) {
    const int c = cpass * 64 + cp * 2;
#pragma unroll
    for (int pp = 0; pp < 8; ++pp) {
      const int wl = pp * 8 + pr;
      const unsigned int val = (unsigned int)lt[c][wl] | ((unsigned int)lt[c + 1][wl] << 16);
      outp[(size_t)wl * 128 + (c >> 1)] = val;
    }
  }
}

// ---------------- conv v2: implicit-GEMM, X-dbuf + counted vmcnt pipeline ----------------
// BM=512 px (4 rows), BN=128, 8 waves. TAPS=9: W from global (L2), 2m x 4n.
// TAPS=1: W LDS-resident (64KB), 4m x 2n.
// EPI: 0=+bias | 1=+bias,leaky | 2=((y+bias+resid)/sqrt2)*s_in | 3=*dscale | 4=+bias,leaky,fp32 NCHW
template <int TAPS, int CTOT, int EPI>
__global__ __launch_bounds__(512, 2) void conv2_mfma(
    const char* __restrict__ wsb, uint32_t xoff,
    const unsigned short* __restrict__ wgl,
    const float* __restrict__ bias, const float* __restrict__ sstyle,
    const unsigned short* __restrict__ resid, unsigned short* __restrict__ outb,
    float* __restrict__ outf) {
  constexpr int ROWS = (TAPS > 1) ? 6 : 4;
  constexpr int WSL  = (TAPS > 1) ? 130 : 128;
  constexpr int XS   = ROWS * WSL * 4;        // 3120 | 2048 (16B slots)
  constexpr int SPT  = (XS + 511) / 512;      // 7 | 4 loads per thread (uniform)
  constexpr int XBP  = SPT * 512 * 16;        // padded buffer bytes: 57344 | 32768
  constexpr int NCB  = CTOT / 32;             // 4 | 8
  constexpr int MF   = (TAPS > 1) ? 16 : 8;
  constexpr int NF   = (TAPS > 1) ? 2 : 4;
  constexpr int MTW  = (TAPS > 1) ? 256 : 128;
  constexpr int LDSZ = 2 * XBP + ((TAPS > 1) ? 0 : 65536);

  __shared__ char smem[LDSZ];

  const int bid0 = (int)blockIdx.x;
  const int bid  = (bid0 & 7) * 32 + (bid0 >> 3);  // bijective XCD swizzle (256%8==0)
  const int b    = bid >> 5;
  const int h0   = (bid & 31) << 2;

  const int tid  = (int)threadIdx.x;
  const int wid  = tid >> 6, lane = tid & 63;
  const int wm   = (TAPS > 1) ? (wid >> 2) : (wid >> 1);
  const int wn   = (TAPS > 1) ? (wid & 3) : (wid & 1);
  const int g    = lane >> 4, l15 = lane & 15;

  // staging source offsets (bytes from wsb), advanced by +64B per cb
  uint32_t offs[SPT];
#pragma unroll
  for (int i = 0; i < SPT; ++i) {
    const int s = tid + i * 512;
    uint32_t off = (uint32_t)OFF_ZERO;
    if (s < XS) {
      const int rws = s >> 2, cpr = s & 3;
      const int row = rws / WSL;
      const int ws  = rws - row * WSL;
      const int c   = cpr ^ (ws & 3);
      if (TAPS > 1) {
        const int hr = h0 + row - 1, w = ws - 1;
        if (hr >= 0 && hr < 128 && w >= 0 && w < 128)
          off = xoff + (uint32_t)(((b * 16384 + hr * 128 + w) * CTOT) + c * 8) * 2u;
      } else {
        off = xoff + (uint32_t)(((b * 16384 + (h0 + row) * 128 + ws) * CTOT) + c * 8) * 2u;
      }
    }
    offs[i] = off;
  }

  if (TAPS == 1) {  // stage full W once: [co][chunk^(co&31)]
#pragma unroll
    for (int i = 0; i < 8; ++i) {
      const int s = tid + i * 512;
      const int co = s >> 5;
      const int c  = (s & 31) ^ (co & 31);
      gload16(wgl + (co * 256 + c * 8), smem + 2 * XBP + (wid * 64 + i * 512) * 16);
    }
  }
  // stage X cb0 -> buf0
#pragma unroll
  for (int i = 0; i < SPT; ++i)
    gload16(wsb + offs[i], smem + (wid * 64 + i * 512) * 16);

  f32x4 acc[MF][NF] = {};

  for (int cb = 0; cb < NCB; ++cb) {
    const int cur = cb & 1;
    if (cb + 1 < NCB) {  // issue next-tile staging, then counted wait
#pragma unroll
      for (int i = 0; i < SPT; ++i) {
        offs[i] += 64;
        gload16(wsb + offs[i], smem + (cur ^ 1) * XBP + (wid * 64 + i * 512) * 16);
      }
      __builtin_amdgcn_sched_barrier(0);
      if (TAPS > 1) asm volatile("s_waitcnt vmcnt(7)" ::: "memory");
      else          asm volatile("s_waitcnt vmcnt(4)" ::: "memory");
    } else {
      __builtin_amdgcn_sched_barrier(0);
      asm volatile("s_waitcnt vmcnt(0)" ::: "memory");
    }
    __builtin_amdgcn_sched_barrier(0);
    __builtin_amdgcn_s_barrier();
    __builtin_amdgcn_sched_barrier(0);

    const char* xb = smem + cur * XBP;
    const int ci0 = cb * 32;
#pragma unroll
    for (int tap = 0; tap < TAPS; ++tap) {
      const int ty = tap / 3, tx = tap - ty * 3;
      f16x8 bfr[NF];
#pragma unroll
      for (int nf = 0; nf < NF; ++nf) {
        const int co = wn * (NF * 16) + nf * 16 + l15;
        if (TAPS > 1)
          bfr[nf] = *(const f16x8*)(wgl + (co * TAPS + tap) * CTOT + ci0 + g * 8);
        else
          bfr[nf] = *(const f16x8*)(smem + 2 * XBP + ((co * 32) + ((4 * cb + g) ^ (co & 31))) * 16);
      }
#pragma unroll
      for (int mf = 0; mf < MF; ++mf) {
        const int mm = wm * MTW + mf * 16 + l15;
        const int ro = mm >> 7, w = mm & 127;
        const int rr = (TAPS > 1) ? (ro + ty) : ro;
        const int ws = (TAPS > 1) ? (w + tx) : w;
        const f16x8 a = *(const f16x8*)(xb + ((rr * WSL + ws) * 4 + (g ^ (ws & 3))) * 16);
#pragma unroll
        for (int nf = 0; nf < NF; ++nf)
          acc[mf][nf] = __builtin_amdgcn_mfma_f32_16x16x32_f16(a, bfr[nf], acc[mf][nf], 0, 0, 0);
      }
    }
    __builtin_amdgcn_sched_barrier(0);
    __builtin_amdgcn_s_barrier();
    __builtin_amdgcn_sched_barrier(0);
  }

  // epilogue: D row = pixel = wm*MTW + mf*16 + 4g + r, col = co
#pragma unroll
  for (int nf = 0; nf < NF; ++nf) {
    const int co = wn * (NF * 16) + nf * 16 + l15;
    float bv = 0.f;
    if (EPI != 3) bv = bias[co];
    float sv = 0.f;
    if (EPI == 2 || EPI == 3) sv = sstyle[b * 128 + co];
#pragma unroll
    for (int mf = 0; mf < MF; ++mf) {
      const int pb = wm * MTW + mf * 16 + 4 * g;
      const int hrow = h0 + (pb >> 7);
      const int w = pb & 127;
      const f32x4 v = acc[mf][nf];
      if (EPI == 4) {  // fp32 NCHW, float4 along w
        float4 o;
        o.x = lrelu(v[0] + bv); o.y = lrelu(v[1] + bv);
        o.z = lrelu(v[2] + bv); o.w = lrelu(v[3] + bv);
        *(float4*)(outf + ((size_t)(b * 128 + co) * 16384 + hrow * 128 + w)) = o;
      } else {
#pragma unroll
        for (int r = 0; r < 4; ++r) {
          const size_t pidx = ((size_t)((b * 128 + hrow) * 128 + (w + r))) * 128 + co;
          float x = v[r];
          if (EPI == 0) x += bv;
          if (EPI == 1) x = lrelu(x + bv);
          if (EPI == 2) x = (x + bv + h2f(resid[pidx])) * 0.70710678118654752f * sv;
          if (EPI == 3) x *= sv;
          outb[pidx] = f2hu(x);
        }
      }
    }
  }
}

// ---------------- launch ----------------
extern "C" void kernel_launch(void* const* d_in, const int* in_sizes, int n_in,
                              void* d_out, int out_size, void* d_ws, size_t ws_size,
                              hipStream_t stream) {
  (void)in_sizes; (void)n_in; (void)out_size; (void)ws_size;
  const float* x1       = (const float*)d_in[0];
  const float* x2       = (const float*)d_in[1];
  const float* xg       = (const float*)d_in[2];
  const float* w_mod    = (const float*)d_in[3];
  const float* b_mod    = (const float*)d_in[4];
  const float* w_style  = (const float*)d_in[5];
  const float* w_bottle = (const float*)d_in[6];
  const float* b_bottle = (const float*)d_in[7];
  const float* w_dc1    = (const float*)d_in[8];
  const float* b_dc1    = (const float*)d_in[9];
  const float* w_dc2    = (const float*)d_in[10];
  const float* b_dc2    = (const float*)d_in[11];
  const float* w_last   = (const float*)d_in[12];
  const float* b_last   = (const float*)d_in[13];
  float* out = (float*)d_out;

  char* ws = (char*)d_ws;
  float* s_in           = (float*)(ws + OFF_SIN);
  float* dscale         = (float*)(ws + OFF_DS);
  float* zerob          = (float*)(ws + OFF_ZERO);
  float* w2buf          = (float*)(ws + OFF_W2);
  unsigned short* wpk   = (unsigned short*)(ws + OFF_WPK);
  unsigned short* wb    = (unsigned short*)(ws + OFF_WB);
  unsigned short* xcat  = (unsigned short*)(ws + OFF_XCAT);
  unsigned short* xb    = (unsigned short*)(ws + OFF_XB);
  unsigned short* y1    = (unsigned short*)(ws + OFF_Y1);

  prep1_kernel<<<2753, 256, 0, stream>>>(xg, w_mod, b_mod, w_style, w_dc1, w_dc2,
                                         w_last, w_bottle, wpk, wb, s_in, w2buf, zerob);
  prep2_kernel<<<256, 256, 0, stream>>>(s_in, w2buf, dscale);
  upcat2_kernel<<<2048, 256, 0, stream>>>(x2, x1, xcat);
  // bottleneck 1x1: xcat -> xb
  conv2_mfma<1, 256, 0><<<256, 512, 0, stream>>>(ws, (uint32_t)OFF_XCAT, wb, b_bottle,
                                                 nullptr, nullptr, xb, nullptr);
  // dc1: xb -> y1
  conv2_mfma<9, 128, 1><<<256, 512, 0, stream>>>(ws, (uint32_t)OFF_XB, wpk, b_dc1,
                                                 nullptr, nullptr, y1, nullptr);
  // dc2 + residual + style input-mod: y1,xb -> xr (reuses XCAT)
  conv2_mfma<9, 128, 2><<<256, 512, 0, stream>>>(ws, (uint32_t)OFF_Y1, wpk + 147456, b_dc2,
                                                 s_in, xb, xcat, nullptr);
  // modulated conv + demod: xr -> xglob (reuses XB)
  conv2_mfma<9, 128, 3><<<256, 512, 0, stream>>>(ws, (uint32_t)OFF_XCAT, wpk + 2 * 147456, nullptr,
                                                 dscale, nullptr, xb, nullptr);
  // conv_last + leaky -> fp32 NCHW out
  conv2_mfma<9, 128, 4><<<256, 512, 0, stream>>>(ws, (uint32_t)OFF_XB, wpk + 3 * 147456, b_last,
                                                 nullptr, nullptr, nullptr, out);
}